// Round 7
// baseline (363.452 us; speedup 1.0000x reference)
//
#include <hip/hip_runtime.h>

#define HID 768
#define NL  17
#define BB  64
#define TT  512

// ===========================================================================
// Kernel 1: emissions = outputs @ fc_w^T + fc_b   (32768x768 @ 768^T x 17)
// 512 thr (8 waves), 64 rows/block, split-8 over K (wave wid owns 96 cols).
// Key fix vs R5: w is staged ONCE into LDS (broadcast reads on lgkmcnt), so
// the VMEM queue contains ONLY the 24-deep per-lane x loads -> one HBM
// latency per wave, then pure LDS+FMA. pacc overlays the w buffer (52.2 KB).
// ===========================================================================
__global__ __launch_bounds__(512) void emis_kernel(const float* __restrict__ x,
                                                   const float* __restrict__ w,
                                                   const float* __restrict__ bias,
                                                   float* __restrict__ y) {
    __shared__ float smem[NL * HID];           // 13056 floats = 52.2 KB

    const int tid  = threadIdx.x;
    const int lane = tid & 63;
    const int wid  = tid >> 6;                 // K-slice 0..7
    const size_t rowbase = (size_t)blockIdx.x * 64;

    // ---- issue w staging loads, 7 deep (oldest in VMEM queue) ----
    const float4* w4 = reinterpret_cast<const float4*>(w);
    float4 tw[7];
#pragma unroll
    for (int j = 0; j < 7; ++j) {
        int idx = tid + 512 * j;
        if (idx > 3263) idx = 3263;            // clamp (redundant load, no branch)
        tw[j] = w4[idx];
    }

    // ---- issue all 24 x loads for this lane's row-slice ----
    const float* rp = x + (rowbase + lane) * HID + wid * 96;
    float4 xr[24];
#pragma unroll
    for (int u = 0; u < 24; ++u)
        xr[u] = *reinterpret_cast<const float4*>(rp + 4 * u);

    // ---- write w to LDS (vmcnt in-order: waits only on tw, not xr) ----
    float4* s4 = reinterpret_cast<float4*>(smem);
#pragma unroll
    for (int j = 0; j < 6; ++j) s4[tid + 512 * j] = tw[j];
    if (tid < 192) s4[tid + 3072] = tw[6];
    __syncthreads();

    // ---- compute: per k, 24 broadcast ds_read_b128 + 96 FMAs ----
    float acc[NL];
#pragma unroll
    for (int k = 0; k < NL; ++k) acc[k] = 0.f;

    for (int k = 0; k < NL; ++k) {
        const float4* wk = reinterpret_cast<const float4*>(&smem[k * HID + wid * 96]);
        float s0 = 0.f, s1 = 0.f, s2 = 0.f, s3 = 0.f;
#pragma unroll
        for (int u = 0; u < 24; ++u) {
            const float4 wv = wk[u];           // wave-uniform -> LDS broadcast
            s0 = fmaf(xr[u].x, wv.x, s0);
            s1 = fmaf(xr[u].y, wv.y, s1);
            s2 = fmaf(xr[u].z, wv.z, s2);
            s3 = fmaf(xr[u].w, wv.w, s3);
        }
        acc[k] = (s0 + s1) + (s2 + s3);
    }

    __syncthreads();                           // all w reads done; reuse smem
    float* pacc = smem;                        // [8][NL][65] = 8840 floats
#pragma unroll
    for (int k = 0; k < NL; ++k) pacc[wid * (NL * 65) + k * 65 + lane] = acc[k];
    __syncthreads();

    for (int o = tid; o < 64 * NL; o += 512) {
        const int r = o / NL, k = o - r * NL;
        float s = bias[k];
#pragma unroll
        for (int sp = 0; sp < 8; ++sp) s += pacc[sp * (NL * 65) + k * 65 + r];
        y[rowbase * NL + o] = s;
    }
}

// ===========================================================================
// Kernel 2: CRF llh. One wave per batch, no LDS. Exp-domain scan; lane j<17
// streams em column j straight from global (L2/L3-hit), double-buffered 8
// steps ahead with exp applied at prefetch. Renorm = exponent extract+ldexp.
// ===========================================================================
__device__ __forceinline__ float bcast(float v, int i) {
    return __uint_as_float(__builtin_amdgcn_readlane(__float_as_uint(v), i));
}

#define CRF_BODY(eem, PN)  \
    { float q0, q1, q2, q3;                                               \
      q0 = bcast(p,  0) * et[0];  q1 = bcast(p,  1) * et[1];              \
      q2 = bcast(p,  2) * et[2];  q3 = bcast(p,  3) * et[3];              \
      q0 = fmaf(bcast(p,  4), et[4],  q0); q1 = fmaf(bcast(p,  5), et[5],  q1); \
      q2 = fmaf(bcast(p,  6), et[6],  q2); q3 = fmaf(bcast(p,  7), et[7],  q3); \
      q0 = fmaf(bcast(p,  8), et[8],  q0); q1 = fmaf(bcast(p,  9), et[9],  q1); \
      q2 = fmaf(bcast(p, 10), et[10], q2); q3 = fmaf(bcast(p, 11), et[11], q3); \
      q0 = fmaf(bcast(p, 12), et[12], q0); q1 = fmaf(bcast(p, 13), et[13], q1); \
      q2 = fmaf(bcast(p, 14), et[14], q2); q3 = fmaf(bcast(p, 15), et[15], q3); \
      q0 = fmaf(bcast(p, 16), et[16], q0);                                \
      PN = ((q0 + q1) + (q2 + q3)) * (eem); }

#define CRF_STEP(eem)      { float pn_; CRF_BODY(eem, pn_); p = pn_; }
#define CRF_STEPG(eem, tt) { float pn_; CRF_BODY(eem, pn_); p = ((tt) < len) ? pn_ : p; }

__global__ __launch_bounds__(64) void crf_kernel(const float* __restrict__ emis,
                                                 const float* __restrict__ st_,
                                                 const float* __restrict__ en_,
                                                 const float* __restrict__ tr_,
                                                 const int* __restrict__ labels,
                                                 const int* __restrict__ mask,
                                                 float* __restrict__ llh) {
    const int b = blockIdx.x;
    const int l = threadIdx.x;
    const float* eb = emis + (size_t)b * TT * NL;
    const int*   lb = labels + b * TT;

    // ---- sequence length (prefix mask) ----
    int lenp = 0;
#pragma unroll
    for (int m = 0; m < 8; ++m) lenp += (mask[b * TT + l + 64 * m] != 0);
#pragma unroll
    for (int off = 32; off; off >>= 1) lenp += __shfl_down(lenp, off);
    const int len = __shfl(lenp, 0);

    // ---- numerator ----
    float np = 0.f;
#pragma unroll
    for (int m = 0; m < 8; ++m) {
        const int t = l + 64 * m;
        int tag = lb[t]; if ((unsigned)tag >= NL) tag = 0;
        if (t < len) {
            if (t == 0) {
                np += st_[tag] + eb[tag];
            } else {
                int tp = lb[t - 1]; if ((unsigned)tp >= NL) tp = 0;
                np += tr_[tp * NL + tag] + eb[t * NL + tag];
            }
            if (t == len - 1) np += en_[tag];
        }
    }
#pragma unroll
    for (int off = 32; off; off >>= 1) np += __shfl_down(np, off);
    const float num = __shfl(np, 0);

    // ---- denominator: exp-domain forward scan ----
    const bool act = (l < NL);
    const int  j   = act ? l : 0;

    float et[NL];
#pragma unroll
    for (int i = 0; i < NL; ++i) et[i] = act ? __expf(tr_[i * NL + j]) : 0.f;

    float p = act ? __expf(st_[j] + eb[j]) : 0.f;
    int   Mi = 0;

    float cur[8];
#pragma unroll
    for (int i = 0; i < 8; ++i) cur[i] = __expf(eb[(1 + i) * NL + j]);

    for (int t0 = 1; t0 < len; t0 += 8) {
        float nx[8];
#pragma unroll
        for (int i = 0; i < 8; ++i) {
            int tn = t0 + 8 + i; tn = (tn < TT) ? tn : (TT - 1);
            nx[i] = eb[tn * NL + j];             // issue; consumed next group
        }
        if (t0 + 8 <= len) {
            CRF_STEP(cur[0]); CRF_STEP(cur[1]); CRF_STEP(cur[2]); CRF_STEP(cur[3]);
            CRF_STEP(cur[4]); CRF_STEP(cur[5]); CRF_STEP(cur[6]); CRF_STEP(cur[7]);
        } else {
            CRF_STEPG(cur[0], t0 + 0); CRF_STEPG(cur[1], t0 + 1);
            CRF_STEPG(cur[2], t0 + 2); CRF_STEPG(cur[3], t0 + 3);
            CRF_STEPG(cur[4], t0 + 4); CRF_STEPG(cur[5], t0 + 5);
            CRF_STEPG(cur[6], t0 + 6); CRF_STEPG(cur[7], t0 + 7);
        }
        // renorm by p0 via exponent extraction (no log/rcp on critical path)
        const unsigned pb = (unsigned)__builtin_amdgcn_readlane((int)__float_as_uint(p), 0);
        const int e = (int)(pb >> 23) - 127;
        Mi += e;
        p = ldexpf(p, -e);
#pragma unroll
        for (int i = 0; i < 8; ++i) cur[i] = __expf(nx[i]);
    }

    float v = act ? p * __expf(en_[j]) : 0.f;
#pragma unroll
    for (int off = 32; off; off >>= 1) v += __shfl_down(v, off);

    if (l == 0) {
        const float denom = (float)Mi * 0.6931471805599453f + __logf(v);
        llh[b] = num - denom;
    }
}

// ===========================================================================
// Kernel 3: loss = -mean(llh)
// ===========================================================================
__global__ __launch_bounds__(64) void loss_kernel(const float* __restrict__ llh,
                                                  float* __restrict__ loss) {
    float v = llh[threadIdx.x];
#pragma unroll
    for (int off = 32; off; off >>= 1) v += __shfl_down(v, off);
    if (threadIdx.x == 0) loss[0] = -(v * (1.0f / BB));
}

// ===========================================================================
extern "C" void kernel_launch(void* const* d_in, const int* in_sizes, int n_in,
                              void* d_out, int out_size, void* d_ws, size_t ws_size,
                              hipStream_t stream) {
    const float* outputs = (const float*)d_in[0];
    const float* fc_w    = (const float*)d_in[1];
    const float* fc_b    = (const float*)d_in[2];
    const float* start_t = (const float*)d_in[3];
    const float* end_t   = (const float*)d_in[4];
    const float* trans   = (const float*)d_in[5];
    const int*   labels  = (const int*)d_in[6];
    const int*   mask    = (const int*)d_in[7];

    float* emis = (float*)d_out;
    float* loss = emis + (size_t)BB * TT * NL;
    float* llh  = (float*)d_ws;

    emis_kernel<<<(BB * TT) / 64, 512, 0, stream>>>(outputs, fc_w, fc_b, emis);
    crf_kernel<<<BB, 64, 0, stream>>>(emis, start_t, end_t, trans, labels, mask, llh);
    loss_kernel<<<1, 64, 0, stream>>>(llh, loss);
}

// Round 8
// 91.715 us; speedup vs baseline: 3.9629x; 3.9629x over previous
//
#include <hip/hip_runtime.h>

#define HID 768
#define NL  17
#define BB  64
#define TT  512

// ===========================================================================
// Kernel 1: emissions = outputs @ fc_w^T + fc_b   (32768x768 @ 768^T x 17)
// Split-8: 512 thr = 8 waves, 64 rows/block; wave wid owns K-slice
// [96*wid, 96*wid+96); lane = row. x: 4 double-buffered batches of 6 float4
// (only VMEM traffic -> in-order vmcnt can't block the prefetch). w: address
// built from readfirstlane(wid) -> provably wave-uniform -> s_load through
// the scalar cache (lgkmcnt), FMA reads the SGPR directly (1 SGPR/VALU ok).
// LDS only for split-K reduce (35.4 KB). ~80 VGPR -> no spill (R6 lesson).
// ===========================================================================
__global__ __launch_bounds__(512) void emis_kernel(const float* __restrict__ x,
                                                   const float* __restrict__ w,
                                                   const float* __restrict__ bias,
                                                   float* __restrict__ y) {
    __shared__ float pacc[8][NL][65];          // 35.4 KB

    const int tid  = threadIdx.x;
    const int lane = tid & 63;
    const int wid  = tid >> 6;
    const int wid_s = __builtin_amdgcn_readfirstlane(wid);   // SGPR wave id
    const size_t rowbase = (size_t)blockIdx.x * 64;
    const float* rp = x + (rowbase + lane) * HID + wid * 96;
    const float* wb = w + wid_s * 96;          // SGPR-only base -> s_load path

    float acc[NL];
#pragma unroll
    for (int k = 0; k < NL; ++k) acc[k] = 0.f;

    float4 ra[6], rb[6];

#define LOADB(dst, bt)                                                        \
    _Pragma("unroll")                                                         \
    for (int u = 0; u < 6; ++u)                                               \
        dst[u] = *reinterpret_cast<const float4*>(rp + (bt) * 24 + u * 4);

#define FMAB(src, bt)                                                         \
    _Pragma("unroll")                                                         \
    for (int k = 0; k < NL; ++k) {                                            \
        const float* wk = wb + k * HID + (bt) * 24;                           \
        float s0 = 0.f, s1 = 0.f, s2 = 0.f, s3 = 0.f;                         \
        _Pragma("unroll")                                                     \
        for (int u = 0; u < 6; ++u) {                                         \
            const float4 wv = *reinterpret_cast<const float4*>(wk + u * 4);   \
            s0 = fmaf(src[u].x, wv.x, s0);                                    \
            s1 = fmaf(src[u].y, wv.y, s1);                                    \
            s2 = fmaf(src[u].z, wv.z, s2);                                    \
            s3 = fmaf(src[u].w, wv.w, s3);                                    \
        }                                                                     \
        acc[k] += (s0 + s1) + (s2 + s3);                                      \
    }

    LOADB(ra, 0);                              // queue: [ra]
    LOADB(rb, 1);                              // queue: [ra, rb]
    FMAB(ra, 0);                               // waits ra; rb stays in flight
    LOADB(ra, 2);                              // queue: [rb, ra]
    FMAB(rb, 1);
    LOADB(rb, 3);
    FMAB(ra, 2);
    FMAB(rb, 3);

#undef LOADB
#undef FMAB

#pragma unroll
    for (int k = 0; k < NL; ++k) pacc[wid][k][lane] = acc[k];
    __syncthreads();

    // reduce 8 partials; outputs contiguous per block: y[blk*1088 + o]
    for (int o = tid; o < 64 * NL; o += 512) {
        const int r = o / NL, k = o - r * NL;
        float s = bias[k];
#pragma unroll
        for (int sp = 0; sp < 8; ++sp) s += pacc[sp][k][r];
        y[rowbase * NL + o] = s;
    }
}

// ===========================================================================
// Kernel 2: CRF llh. One wave per batch, no LDS. Exp-domain scan; lane j<17
// streams em column j straight from global (L2/L3-hit), double-buffered 8
// steps ahead with exp applied at prefetch. Renorm = exponent extract+ldexp.
// ===========================================================================
__device__ __forceinline__ float bcast(float v, int i) {
    return __uint_as_float(__builtin_amdgcn_readlane(__float_as_uint(v), i));
}

#define CRF_BODY(eem, PN)  \
    { float q0, q1, q2, q3;                                               \
      q0 = bcast(p,  0) * et[0];  q1 = bcast(p,  1) * et[1];              \
      q2 = bcast(p,  2) * et[2];  q3 = bcast(p,  3) * et[3];              \
      q0 = fmaf(bcast(p,  4), et[4],  q0); q1 = fmaf(bcast(p,  5), et[5],  q1); \
      q2 = fmaf(bcast(p,  6), et[6],  q2); q3 = fmaf(bcast(p,  7), et[7],  q3); \
      q0 = fmaf(bcast(p,  8), et[8],  q0); q1 = fmaf(bcast(p,  9), et[9],  q1); \
      q2 = fmaf(bcast(p, 10), et[10], q2); q3 = fmaf(bcast(p, 11), et[11], q3); \
      q0 = fmaf(bcast(p, 12), et[12], q0); q1 = fmaf(bcast(p, 13), et[13], q1); \
      q2 = fmaf(bcast(p, 14), et[14], q2); q3 = fmaf(bcast(p, 15), et[15], q3); \
      q0 = fmaf(bcast(p, 16), et[16], q0);                                \
      PN = ((q0 + q1) + (q2 + q3)) * (eem); }

#define CRF_STEP(eem)      { float pn_; CRF_BODY(eem, pn_); p = pn_; }
#define CRF_STEPG(eem, tt) { float pn_; CRF_BODY(eem, pn_); p = ((tt) < len) ? pn_ : p; }

__global__ __launch_bounds__(64) void crf_kernel(const float* __restrict__ emis,
                                                 const float* __restrict__ st_,
                                                 const float* __restrict__ en_,
                                                 const float* __restrict__ tr_,
                                                 const int* __restrict__ labels,
                                                 const int* __restrict__ mask,
                                                 float* __restrict__ llh) {
    const int b = blockIdx.x;
    const int l = threadIdx.x;
    const float* eb = emis + (size_t)b * TT * NL;
    const int*   lb = labels + b * TT;

    // ---- sequence length (prefix mask) ----
    int lenp = 0;
#pragma unroll
    for (int m = 0; m < 8; ++m) lenp += (mask[b * TT + l + 64 * m] != 0);
#pragma unroll
    for (int off = 32; off; off >>= 1) lenp += __shfl_down(lenp, off);
    const int len = __shfl(lenp, 0);

    // ---- numerator ----
    float np = 0.f;
#pragma unroll
    for (int m = 0; m < 8; ++m) {
        const int t = l + 64 * m;
        int tag = lb[t]; if ((unsigned)tag >= NL) tag = 0;
        if (t < len) {
            if (t == 0) {
                np += st_[tag] + eb[tag];
            } else {
                int tp = lb[t - 1]; if ((unsigned)tp >= NL) tp = 0;
                np += tr_[tp * NL + tag] + eb[t * NL + tag];
            }
            if (t == len - 1) np += en_[tag];
        }
    }
#pragma unroll
    for (int off = 32; off; off >>= 1) np += __shfl_down(np, off);
    const float num = __shfl(np, 0);

    // ---- denominator: exp-domain forward scan ----
    const bool act = (l < NL);
    const int  j   = act ? l : 0;

    float et[NL];
#pragma unroll
    for (int i = 0; i < NL; ++i) et[i] = act ? __expf(tr_[i * NL + j]) : 0.f;

    float p = act ? __expf(st_[j] + eb[j]) : 0.f;
    int   Mi = 0;

    float cur[8];
#pragma unroll
    for (int i = 0; i < 8; ++i) cur[i] = __expf(eb[(1 + i) * NL + j]);

    for (int t0 = 1; t0 < len; t0 += 8) {
        float nx[8];
#pragma unroll
        for (int i = 0; i < 8; ++i) {
            int tn = t0 + 8 + i; tn = (tn < TT) ? tn : (TT - 1);
            nx[i] = eb[tn * NL + j];             // issue; consumed next group
        }
        if (t0 + 8 <= len) {
            CRF_STEP(cur[0]); CRF_STEP(cur[1]); CRF_STEP(cur[2]); CRF_STEP(cur[3]);
            CRF_STEP(cur[4]); CRF_STEP(cur[5]); CRF_STEP(cur[6]); CRF_STEP(cur[7]);
        } else {
            CRF_STEPG(cur[0], t0 + 0); CRF_STEPG(cur[1], t0 + 1);
            CRF_STEPG(cur[2], t0 + 2); CRF_STEPG(cur[3], t0 + 3);
            CRF_STEPG(cur[4], t0 + 4); CRF_STEPG(cur[5], t0 + 5);
            CRF_STEPG(cur[6], t0 + 6); CRF_STEPG(cur[7], t0 + 7);
        }
        // renorm by p0 via exponent extraction (no log/rcp on critical path)
        const unsigned pb = (unsigned)__builtin_amdgcn_readlane((int)__float_as_uint(p), 0);
        const int e = (int)(pb >> 23) - 127;
        Mi += e;
        p = ldexpf(p, -e);
#pragma unroll
        for (int i = 0; i < 8; ++i) cur[i] = __expf(nx[i]);
    }

    float v = act ? p * __expf(en_[j]) : 0.f;
#pragma unroll
    for (int off = 32; off; off >>= 1) v += __shfl_down(v, off);

    if (l == 0) {
        const float denom = (float)Mi * 0.6931471805599453f + __logf(v);
        llh[b] = num - denom;
    }
}

// ===========================================================================
// Kernel 3: loss = -mean(llh)
// ===========================================================================
__global__ __launch_bounds__(64) void loss_kernel(const float* __restrict__ llh,
                                                  float* __restrict__ loss) {
    float v = llh[threadIdx.x];
#pragma unroll
    for (int off = 32; off; off >>= 1) v += __shfl_down(v, off);
    if (threadIdx.x == 0) loss[0] = -(v * (1.0f / BB));
}

// ===========================================================================
extern "C" void kernel_launch(void* const* d_in, const int* in_sizes, int n_in,
                              void* d_out, int out_size, void* d_ws, size_t ws_size,
                              hipStream_t stream) {
    const float* outputs = (const float*)d_in[0];
    const float* fc_w    = (const float*)d_in[1];
    const float* fc_b    = (const float*)d_in[2];
    const float* start_t = (const float*)d_in[3];
    const float* end_t   = (const float*)d_in[4];
    const float* trans   = (const float*)d_in[5];
    const int*   labels  = (const int*)d_in[6];
    const int*   mask    = (const int*)d_in[7];

    float* emis = (float*)d_out;
    float* loss = emis + (size_t)BB * TT * NL;
    float* llh  = (float*)d_ws;

    emis_kernel<<<(BB * TT) / 64, 512, 0, stream>>>(outputs, fc_w, fc_b, emis);
    crf_kernel<<<BB, 64, 0, stream>>>(emis, start_t, end_t, trans, labels, mask, llh);
    loss_kernel<<<1, 64, 0, stream>>>(llh, loss);
}

// Round 9
// 90.901 us; speedup vs baseline: 3.9983x; 1.0089x over previous
//
#include <hip/hip_runtime.h>

#define HID 768
#define NL  17
#define BB  64
#define TT  512

// ===========================================================================
// Kernel 1: emissions = outputs @ fc_w^T + fc_b   (32768x768 @ 768^T x 17)
// Split-8: 512 thr = 8 waves, 64 rows/block; wave wid owns K-slice
// [96*wid, 96*wid+96); lane = row. x: 3-deep register pipeline of 6-float4
// batches, PINNED with sched_barrier(0) so the loads stay issued ahead of the
// FMA blocks (R7: compiler sank them -> VGPR 44, 1.37 TB/s, latency-bound).
// w: SGPR base via readfirstlane -> s_load scalar path (lgkmcnt queue,
// doesn't block the x vmcnt queue). LDS only for split-K reduce (35.4 KB).
// ===========================================================================
__global__ __launch_bounds__(512) void emis_kernel(const float* __restrict__ x,
                                                   const float* __restrict__ w,
                                                   const float* __restrict__ bias,
                                                   float* __restrict__ y) {
    __shared__ float pacc[8][NL][65];          // 35.4 KB

    const int tid  = threadIdx.x;
    const int lane = tid & 63;
    const int wid  = tid >> 6;
    const int wid_s = __builtin_amdgcn_readfirstlane(wid);   // SGPR wave id
    const size_t rowbase = (size_t)blockIdx.x * 64;
    const float* rp = x + (rowbase + lane) * HID + wid * 96;
    const float* wb = w + wid_s * 96;          // SGPR-only base -> s_load path

    float acc[NL];
#pragma unroll
    for (int k = 0; k < NL; ++k) acc[k] = 0.f;

    float4 r0[6], r1[6], r2[6];

#define LOADB(dst, bt)                                                        \
    _Pragma("unroll")                                                         \
    for (int u = 0; u < 6; ++u)                                               \
        dst[u] = *reinterpret_cast<const float4*>(rp + (bt) * 24 + u * 4);

#define FMAB(src, bt)                                                         \
    _Pragma("unroll")                                                         \
    for (int k = 0; k < NL; ++k) {                                            \
        const float* wk = wb + k * HID + (bt) * 24;                           \
        float s0 = 0.f, s1 = 0.f, s2 = 0.f, s3 = 0.f;                         \
        _Pragma("unroll")                                                     \
        for (int u = 0; u < 6; ++u) {                                         \
            const float4 wv = *reinterpret_cast<const float4*>(wk + u * 4);   \
            s0 = fmaf(src[u].x, wv.x, s0);                                    \
            s1 = fmaf(src[u].y, wv.y, s1);                                    \
            s2 = fmaf(src[u].z, wv.z, s2);                                    \
            s3 = fmaf(src[u].w, wv.w, s3);                                    \
        }                                                                     \
        acc[k] += (s0 + s1) + (s2 + s3);                                      \
    }

#define SBAR() __builtin_amdgcn_sched_barrier(0)

    LOADB(r0, 0);                              // queue: [r0]
    LOADB(r1, 1);                              // queue: [r0,r1]
    LOADB(r2, 2);                              // queue: [r0,r1,r2]
    SBAR();
    FMAB(r0, 0);                               // waits r0 only (vmcnt 12)
    SBAR();
    LOADB(r0, 3);                              // queue: [r1,r2,r0']
    SBAR();
    FMAB(r1, 1);                               // vmcnt 12
    SBAR();
    FMAB(r2, 2);
    SBAR();
    FMAB(r0, 3);

#undef LOADB
#undef FMAB
#undef SBAR

#pragma unroll
    for (int k = 0; k < NL; ++k) pacc[wid][k][lane] = acc[k];
    __syncthreads();

    // reduce 8 partials; outputs contiguous per block: y[blk*1088 + o]
    for (int o = tid; o < 64 * NL; o += 512) {
        const int r = o / NL, k = o - r * NL;
        float s = bias[k];
#pragma unroll
        for (int sp = 0; sp < 8; ++sp) s += pacc[sp][k][r];
        y[rowbase * NL + o] = s;
    }
}

// ===========================================================================
// Kernel 2: CRF llh. One wave per batch, no LDS. Exp-domain scan; lane j<17
// streams em column j straight from global (L2/L3-hit), double-buffered 8
// steps ahead with exp applied at prefetch. Renorm = exponent extract+ldexp.
// ===========================================================================
__device__ __forceinline__ float bcast(float v, int i) {
    return __uint_as_float(__builtin_amdgcn_readlane(__float_as_uint(v), i));
}

#define CRF_BODY(eem, PN)  \
    { float q0, q1, q2, q3;                                               \
      q0 = bcast(p,  0) * et[0];  q1 = bcast(p,  1) * et[1];              \
      q2 = bcast(p,  2) * et[2];  q3 = bcast(p,  3) * et[3];              \
      q0 = fmaf(bcast(p,  4), et[4],  q0); q1 = fmaf(bcast(p,  5), et[5],  q1); \
      q2 = fmaf(bcast(p,  6), et[6],  q2); q3 = fmaf(bcast(p,  7), et[7],  q3); \
      q0 = fmaf(bcast(p,  8), et[8],  q0); q1 = fmaf(bcast(p,  9), et[9],  q1); \
      q2 = fmaf(bcast(p, 10), et[10], q2); q3 = fmaf(bcast(p, 11), et[11], q3); \
      q0 = fmaf(bcast(p, 12), et[12], q0); q1 = fmaf(bcast(p, 13), et[13], q1); \
      q2 = fmaf(bcast(p, 14), et[14], q2); q3 = fmaf(bcast(p, 15), et[15], q3); \
      q0 = fmaf(bcast(p, 16), et[16], q0);                                \
      PN = ((q0 + q1) + (q2 + q3)) * (eem); }

#define CRF_STEP(eem)      { float pn_; CRF_BODY(eem, pn_); p = pn_; }
#define CRF_STEPG(eem, tt) { float pn_; CRF_BODY(eem, pn_); p = ((tt) < len) ? pn_ : p; }

__global__ __launch_bounds__(64) void crf_kernel(const float* __restrict__ emis,
                                                 const float* __restrict__ st_,
                                                 const float* __restrict__ en_,
                                                 const float* __restrict__ tr_,
                                                 const int* __restrict__ labels,
                                                 const int* __restrict__ mask,
                                                 float* __restrict__ llh) {
    const int b = blockIdx.x;
    const int l = threadIdx.x;
    const float* eb = emis + (size_t)b * TT * NL;
    const int*   lb = labels + b * TT;

    // ---- sequence length (prefix mask) ----
    int lenp = 0;
#pragma unroll
    for (int m = 0; m < 8; ++m) lenp += (mask[b * TT + l + 64 * m] != 0);
#pragma unroll
    for (int off = 32; off; off >>= 1) lenp += __shfl_down(lenp, off);
    const int len = __shfl(lenp, 0);

    // ---- numerator ----
    float np = 0.f;
#pragma unroll
    for (int m = 0; m < 8; ++m) {
        const int t = l + 64 * m;
        int tag = lb[t]; if ((unsigned)tag >= NL) tag = 0;
        if (t < len) {
            if (t == 0) {
                np += st_[tag] + eb[tag];
            } else {
                int tp = lb[t - 1]; if ((unsigned)tp >= NL) tp = 0;
                np += tr_[tp * NL + tag] + eb[t * NL + tag];
            }
            if (t == len - 1) np += en_[tag];
        }
    }
#pragma unroll
    for (int off = 32; off; off >>= 1) np += __shfl_down(np, off);
    const float num = __shfl(np, 0);

    // ---- denominator: exp-domain forward scan ----
    const bool act = (l < NL);
    const int  j   = act ? l : 0;

    float et[NL];
#pragma unroll
    for (int i = 0; i < NL; ++i) et[i] = act ? __expf(tr_[i * NL + j]) : 0.f;

    float p = act ? __expf(st_[j] + eb[j]) : 0.f;
    int   Mi = 0;

    float cur[8];
#pragma unroll
    for (int i = 0; i < 8; ++i) cur[i] = __expf(eb[(1 + i) * NL + j]);

    for (int t0 = 1; t0 < len; t0 += 8) {
        float nx[8];
#pragma unroll
        for (int i = 0; i < 8; ++i) {
            int tn = t0 + 8 + i; tn = (tn < TT) ? tn : (TT - 1);
            nx[i] = eb[tn * NL + j];             // issue; consumed next group
        }
        if (t0 + 8 <= len) {
            CRF_STEP(cur[0]); CRF_STEP(cur[1]); CRF_STEP(cur[2]); CRF_STEP(cur[3]);
            CRF_STEP(cur[4]); CRF_STEP(cur[5]); CRF_STEP(cur[6]); CRF_STEP(cur[7]);
        } else {
            CRF_STEPG(cur[0], t0 + 0); CRF_STEPG(cur[1], t0 + 1);
            CRF_STEPG(cur[2], t0 + 2); CRF_STEPG(cur[3], t0 + 3);
            CRF_STEPG(cur[4], t0 + 4); CRF_STEPG(cur[5], t0 + 5);
            CRF_STEPG(cur[6], t0 + 6); CRF_STEPG(cur[7], t0 + 7);
        }
        // renorm by p0 via exponent extraction (no log/rcp on critical path)
        const unsigned pb = (unsigned)__builtin_amdgcn_readlane((int)__float_as_uint(p), 0);
        const int e = (int)(pb >> 23) - 127;
        Mi += e;
        p = ldexpf(p, -e);
#pragma unroll
        for (int i = 0; i < 8; ++i) cur[i] = __expf(nx[i]);
    }

    float v = act ? p * __expf(en_[j]) : 0.f;
#pragma unroll
    for (int off = 32; off; off >>= 1) v += __shfl_down(v, off);

    if (l == 0) {
        const float denom = (float)Mi * 0.6931471805599453f + __logf(v);
        llh[b] = num - denom;
    }
}

// ===========================================================================
// Kernel 3: loss = -mean(llh)
// ===========================================================================
__global__ __launch_bounds__(64) void loss_kernel(const float* __restrict__ llh,
                                                  float* __restrict__ loss) {
    float v = llh[threadIdx.x];
#pragma unroll
    for (int off = 32; off; off >>= 1) v += __shfl_down(v, off);
    if (threadIdx.x == 0) loss[0] = -(v * (1.0f / BB));
}

// ===========================================================================
extern "C" void kernel_launch(void* const* d_in, const int* in_sizes, int n_in,
                              void* d_out, int out_size, void* d_ws, size_t ws_size,
                              hipStream_t stream) {
    const float* outputs = (const float*)d_in[0];
    const float* fc_w    = (const float*)d_in[1];
    const float* fc_b    = (const float*)d_in[2];
    const float* start_t = (const float*)d_in[3];
    const float* end_t   = (const float*)d_in[4];
    const float* trans   = (const float*)d_in[5];
    const int*   labels  = (const int*)d_in[6];
    const int*   mask    = (const int*)d_in[7];

    float* emis = (float*)d_out;
    float* loss = emis + (size_t)BB * TT * NL;
    float* llh  = (float*)d_ws;

    emis_kernel<<<(BB * TT) / 64, 512, 0, stream>>>(outputs, fc_w, fc_b, emis);
    crf_kernel<<<BB, 64, 0, stream>>>(emis, start_t, end_t, trans, labels, mask, llh);
    loss_kernel<<<1, 64, 0, stream>>>(llh, loss);
}